// Round 3
// baseline (1277.749 us; speedup 1.0000x reference)
//
#include <hip/hip_runtime.h>
#include <cstdint>
#include <cstddef>

typedef __attribute__((ext_vector_type(8))) _Float16 half8;
typedef __attribute__((ext_vector_type(4))) float f32x4;

#define N_ROWS 16384
#define K_CODES 8192
#define D_DIM 256
#define MARGIN 5e-4f
#define SCL (-0.000244140625f) /* -2/8192, exact */

// ===== MFMA-path ws layout (bytes) =====
#define WS_ZF 0           /* 16384*256 f16 tiled+swizzled  (8 MB)   */
#define WS_EF 8388608     /* 8192*256  f16 tiled+swizzled  (4 MB)   */
#define WS_WMIN 12582912  /* 16384 u64 packed (score,idx)           */
#define WS_Z2 12713984    /* 16384 f32                              */
#define WS_E2 12779520    /* 8192  f32                              */
#define WS_AMIN 12812288  /* 16384 u32 float-bits approx min        */
#define WS_PART 12877824  /* 256 f64 loss partials                  */
#define WS_NEED 12879872

// ===== fallback (round-2) ws layout =====
#define FB_WMIN 0
#define FB_Z2 131072
#define FB_E2 196608
#define FB_PART 229376

__device__ __forceinline__ void gload16(const void* g, void* l) {
    __builtin_amdgcn_global_load_lds(
        (const __attribute__((address_space(1))) void*)g,
        (__attribute__((address_space(3))) void*)l, 16, 0, 0);
}

// ---------------------------------------------------------------------------
// k_prep: row norms z2/e2 (round-2-identical shuffle tree), init wmin/amin/partials
// ---------------------------------------------------------------------------
__global__ __launch_bounds__(256) void k_prep(const float* __restrict__ z,
                                              const float* __restrict__ e,
                                              float* __restrict__ z2,
                                              float* __restrict__ e2,
                                              unsigned long long* __restrict__ wmin,
                                              double* __restrict__ partials,
                                              unsigned* __restrict__ amin) {
    int tid = threadIdx.x;
    int w = tid >> 6, lane = tid & 63;
    int row = blockIdx.x * 4 + w;
    if (blockIdx.x == 0) partials[tid] = 0.0;
    const float* src = (row < N_ROWS) ? (z + (size_t)row * D_DIM)
                                      : (e + (size_t)(row - N_ROWS) * D_DIM);
    float4 v = reinterpret_cast<const float4*>(src)[lane];
    float s = v.x * v.x;
    s = fmaf(v.y, v.y, s);
    s = fmaf(v.z, v.z, s);
    s = fmaf(v.w, v.w, s);
    #pragma unroll
    for (int off = 32; off >= 1; off >>= 1) s += __shfl_down(s, off);
    if (lane == 0) {
        if (row < N_ROWS) {
            z2[row] = s;
            wmin[row] = ~0ull;
            if (amin) amin[row] = 0x7F800000u; // +inf bits
        } else {
            e2[row - N_ROWS] = s;
        }
    }
}

// ---------------------------------------------------------------------------
// k_conv: fp32 -> f16 (e scaled by 8192), tiled [blk128][chunk64] with
// granule XOR swizzle so linear global_load_lds + XOR'd ds_read is conflict-free
// ---------------------------------------------------------------------------
__global__ __launch_bounds__(256) void k_conv(const float* __restrict__ z,
                                              const float* __restrict__ e,
                                              _Float16* __restrict__ zf,
                                              _Float16* __restrict__ ef) {
    int b = blockIdx.x;
    const float* src;
    _Float16* dst;
    float scl;
    if (b < 512) { // z tiles: 128 mblks x 4 chunks
        int mblk = b >> 2, c = b & 3;
        src = z + (size_t)mblk * 128 * D_DIM + c * 64;
        dst = zf + (size_t)b * 8192;
        scl = 1.0f;
    } else {       // e tiles: 64 nblks x 4 chunks
        int bb = b - 512;
        int nblk = bb >> 2, c = bb & 3;
        src = e + (size_t)nblk * 128 * D_DIM + c * 64;
        dst = ef + (size_t)bb * 8192;
        scl = 8192.0f;
    }
    int t = threadIdx.x;
    #pragma unroll
    for (int i = 0; i < 4; ++i) {
        int gid = t + i * 256;           // granule 0..1023 (8 f16 each)
        int r = gid >> 3, gin = gid & 7; // row 0..127, granule-in-row
        const float* s = src + (size_t)r * D_DIM + gin * 8;
        float4 v0 = ((const float4*)s)[0];
        float4 v1 = ((const float4*)s)[1];
        half8 h;
        h[0] = (_Float16)(v0.x * scl); h[1] = (_Float16)(v0.y * scl);
        h[2] = (_Float16)(v0.z * scl); h[3] = (_Float16)(v0.w * scl);
        h[4] = (_Float16)(v1.x * scl); h[5] = (_Float16)(v1.y * scl);
        h[6] = (_Float16)(v1.z * scl); h[7] = (_Float16)(v1.w * scl);
        int dg = r * 8 + (gin ^ (r & 7)); // XOR swizzle on granule index
        *(half8*)(dst + (size_t)dg * 8) = h;
    }
}

// ---------------------------------------------------------------------------
// k_mfma: 128x128 tile, 4 waves (2x2 of 64x64), D=256 in 4 chunks of 64.
// MODE 0: approx-min pass (subset of codes) -> amin[row] (u32 float bits)
// MODE 1: select s~ <= amin+M, exact sequential-fp32 rescore, packed atomicMin
// ---------------------------------------------------------------------------
template <int MODE>
__global__ __launch_bounds__(256) void k_mfma(const _Float16* __restrict__ zf,
                                              const _Float16* __restrict__ ef,
                                              const float* __restrict__ z2,
                                              const float* __restrict__ e2,
                                              const float* __restrict__ zfull,
                                              const float* __restrict__ efull,
                                              unsigned* __restrict__ amin,
                                              unsigned long long* __restrict__ wmin) {
    __shared__ _Float16 As[8192]; // 16 KB: [128 r][64 d] swizzled
    __shared__ _Float16 Bs[8192];
    const int tid = threadIdx.x;
    const int wid = tid >> 6, lane = tid & 63;
    const int l15 = lane & 15, l4 = lane >> 4;
    const int mblk = blockIdx.x, nblk = blockIdx.y;
    const int wr = wid >> 1, wc = wid & 1;

    f32x4 acc[4][4];
    #pragma unroll
    for (int mi = 0; mi < 4; ++mi)
        #pragma unroll
        for (int ni = 0; ni < 4; ++ni) acc[mi][ni] = (f32x4){0.f, 0.f, 0.f, 0.f};

    for (int c = 0; c < 4; ++c) {
        const _Float16* zt = zf + (size_t)(mblk * 4 + c) * 8192;
        const _Float16* et = ef + (size_t)(nblk * 4 + c) * 8192;
        #pragma unroll
        for (int i = 0; i < 4; ++i) {
            int off = i * 4096 + tid * 16;
            gload16((const char*)zt + off, (char*)&As[0] + off);
            gload16((const char*)et + off, (char*)&Bs[0] + off);
        }
        asm volatile("s_waitcnt vmcnt(0)" ::: "memory");
        __syncthreads();

        #pragma unroll
        for (int ds = 0; ds < 2; ++ds) {
            half8 av[4], bv[4];
            #pragma unroll
            for (int mi = 0; mi < 4; ++mi) {
                int rr = wr * 64 + mi * 16 + l15;
                int byte = (rr * 128 + ds * 64 + l4 * 16) ^ ((rr & 7) << 4);
                av[mi] = *(const half8*)((const char*)&As[0] + byte);
            }
            #pragma unroll
            for (int ni = 0; ni < 4; ++ni) {
                int rr = wc * 64 + ni * 16 + l15;
                int byte = (rr * 128 + ds * 64 + l4 * 16) ^ ((rr & 7) << 4);
                bv[ni] = *(const half8*)((const char*)&Bs[0] + byte);
            }
            #pragma unroll
            for (int mi = 0; mi < 4; ++mi)
                #pragma unroll
                for (int ni = 0; ni < 4; ++ni)
                    acc[mi][ni] = __builtin_amdgcn_mfma_f32_16x16x32_f16(
                        av[mi], bv[ni], acc[mi][ni], 0, 0, 0);
        }
        __syncthreads();
    }

    // epilogue — C/D frag: col = lane&15, row = (lane>>4)*4 + reg
    const int row0 = mblk * 128 + wr * 64;
    const int col0 = nblk * 128 + wc * 64;
    float e2c[4];
    #pragma unroll
    for (int ni = 0; ni < 4; ++ni) e2c[ni] = e2[col0 + ni * 16 + l15];

    if (MODE == 0) {
        #pragma unroll
        for (int mi = 0; mi < 4; ++mi) {
            #pragma unroll
            for (int r = 0; r < 4; ++r) {
                int row = row0 + mi * 16 + l4 * 4 + r;
                float z2v = z2[row];
                float m = __builtin_inff();
                #pragma unroll
                for (int ni = 0; ni < 4; ++ni) {
                    float s = fmaf(SCL, acc[mi][ni][r], z2v + e2c[ni]);
                    m = fminf(m, s);
                }
                #pragma unroll
                for (int x = 1; x < 16; x <<= 1) m = fminf(m, __shfl_xor(m, x));
                if (l15 == 0) atomicMin(&amin[row], __float_as_uint(m));
            }
        }
    } else {
        #pragma unroll
        for (int mi = 0; mi < 4; ++mi) {
            #pragma unroll
            for (int r = 0; r < 4; ++r) {
                int row = row0 + mi * 16 + l4 * 4 + r;
                float z2v = z2[row];
                float thr = __uint_as_float(amin[row]) + MARGIN;
                #pragma unroll
                for (int ni = 0; ni < 4; ++ni) {
                    float s = fmaf(SCL, acc[mi][ni][r], z2v + e2c[ni]);
                    if (s <= thr) {
                        int col = col0 + ni * 16 + l15;
                        const float* zp = zfull + (size_t)row * D_DIM;
                        const float* ep = efull + (size_t)col * D_DIM;
                        float ax = 0.f; // exact: sequential fp32 fma, d ascending
                        for (int d = 0; d < D_DIM; ++d) ax = fmaf(zp[d], ep[d], ax);
                        float se = fmaf(-2.0f, ax, z2v + e2c[ni]);
                        unsigned long long key =
                            ((unsigned long long)__float_as_uint(se) << 32) | (unsigned)col;
                        atomicMin(&wmin[row], key);
                    }
                }
            }
        }
    }
}

// ---------------------------------------------------------------------------
// round-2 fallback fused fp32 argmin (used only if ws too small)
// ---------------------------------------------------------------------------
#define BN 128
#define BK 128
#define BD 32
#define KSPLIT 8
#define KSLICE (K_CODES / KSPLIT)
#define NT_TILES (KSLICE / BK)
#define LDS_STRIDE 132

__global__ __launch_bounds__(256) void k_argmin_fb(const float* __restrict__ z,
                                                   const float* __restrict__ e,
                                                   const float* __restrict__ z2,
                                                   const float* __restrict__ e2,
                                                   unsigned long long* __restrict__ wmin) {
    __shared__ float zs[BD][LDS_STRIDE];
    __shared__ float es[BD][LDS_STRIDE];
    const int tid = threadIdx.x;
    const int ty = tid >> 4, tx = tid & 15;
    const int row0 = blockIdx.x * BN;
    const int k0 = blockIdx.y * KSLICE;

    float z2r[8];
    #pragma unroll
    for (int i = 0; i < 8; i++) z2r[i] = z2[row0 + ty * 8 + i];
    float rmin[8];
    int ridx[8];
    #pragma unroll
    for (int i = 0; i < 8; i++) { rmin[i] = INFINITY; ridx[i] = 0; }

    for (int kt = 0; kt < NT_TILES; kt++) {
        const int kbase = k0 + kt * BK;
        float acc[8][8];
        #pragma unroll
        for (int i = 0; i < 8; i++)
            #pragma unroll
            for (int j = 0; j < 8; j++) acc[i][j] = 0.f;
        for (int dc = 0; dc < D_DIM; dc += BD) {
            __syncthreads();
            #pragma unroll
            for (int i = 0; i < 4; i++) {
                int li = tid * 4 + i;
                int r = li >> 3;
                int d0 = (li & 7) * 4;
                float4 vz = *reinterpret_cast<const float4*>(
                    z + (size_t)(row0 + r) * D_DIM + dc + d0);
                zs[d0 + 0][r] = vz.x; zs[d0 + 1][r] = vz.y;
                zs[d0 + 2][r] = vz.z; zs[d0 + 3][r] = vz.w;
                float4 ve = *reinterpret_cast<const float4*>(
                    e + (size_t)(kbase + r) * D_DIM + dc + d0);
                es[d0 + 0][r] = ve.x; es[d0 + 1][r] = ve.y;
                es[d0 + 2][r] = ve.z; es[d0 + 3][r] = ve.w;
            }
            __syncthreads();
            #pragma unroll 2
            for (int d = 0; d < BD; d++) {
                float4 za = *reinterpret_cast<const float4*>(&zs[d][ty * 8]);
                float4 zb = *reinterpret_cast<const float4*>(&zs[d][ty * 8 + 4]);
                float4 ea = *reinterpret_cast<const float4*>(&es[d][tx * 8]);
                float4 eb = *reinterpret_cast<const float4*>(&es[d][tx * 8 + 4]);
                float zr[8] = {za.x, za.y, za.z, za.w, zb.x, zb.y, zb.z, zb.w};
                float er[8] = {ea.x, ea.y, ea.z, ea.w, eb.x, eb.y, eb.z, eb.w};
                #pragma unroll
                for (int i = 0; i < 8; i++)
                    #pragma unroll
                    for (int j = 0; j < 8; j++)
                        acc[i][j] = fmaf(zr[i], er[j], acc[i][j]);
            }
        }
        float e2c[8];
        #pragma unroll
        for (int j = 0; j < 8; j++) e2c[j] = e2[kbase + tx * 8 + j];
        #pragma unroll
        for (int i = 0; i < 8; i++) {
            #pragma unroll
            for (int j = 0; j < 8; j++) {
                float C = z2r[i] + e2c[j];
                float s = fmaf(-2.0f, acc[i][j], C);
                if (s < rmin[i]) { rmin[i] = s; ridx[i] = kbase + tx * 8 + j; }
            }
        }
    }
    #pragma unroll
    for (int i = 0; i < 8; i++) {
        unsigned long long key =
            ((unsigned long long)__float_as_uint(rmin[i]) << 32) | (unsigned)ridx[i];
        #pragma unroll
        for (int m = 8; m >= 1; m >>= 1) {
            unsigned long long o = __shfl_xor(key, m);
            if (o < key) key = o;
        }
        if (tx == 0) atomicMin(wmin + row0 + ty * 8 + i, key);
    }
}

// ---------------------------------------------------------------------------
__global__ __launch_bounds__(64) void k_gather(const float* __restrict__ z,
                                               const float* __restrict__ e,
                                               const unsigned long long* __restrict__ wmin,
                                               float* __restrict__ out,
                                               double* __restrict__ partials) {
    int row = blockIdx.x;
    int lane = threadIdx.x;
    unsigned idx = (unsigned)(wmin[row] & 0xFFFFFFFFull);
    float4 q = reinterpret_cast<const float4*>(e + (size_t)idx * D_DIM)[lane];
    float4 zv = reinterpret_cast<const float4*>(z + (size_t)row * D_DIM)[lane];
    float dx = q.x - zv.x, dy = q.y - zv.y, dz = q.z - zv.z, dw = q.w - zv.w;
    float4 o;
    o.x = zv.x + dx; o.y = zv.y + dy; o.z = zv.z + dz; o.w = zv.w + dw;
    reinterpret_cast<float4*>(out + (size_t)row * D_DIM)[lane] = o;
    float s = dx * dx;
    s = fmaf(dy, dy, s);
    s = fmaf(dz, dz, s);
    s = fmaf(dw, dw, s);
    #pragma unroll
    for (int off = 32; off >= 1; off >>= 1) s += __shfl_down(s, off);
    if (lane == 0) atomicAdd(&partials[row & 255], (double)s);
}

__global__ __launch_bounds__(64) void k_finalize(const double* __restrict__ partials,
                                                 float* __restrict__ out_loss) {
    int lane = threadIdx.x;
    double v = partials[lane] + partials[lane + 64] +
               partials[lane + 128] + partials[lane + 192];
    #pragma unroll
    for (int off = 32; off >= 1; off >>= 1) v += __shfl_down(v, off);
    if (lane == 0) {
        float L = (float)(v / (double)((size_t)N_ROWS * D_DIM));
        out_loss[0] = L + 0.25f * L;
    }
}

extern "C" void kernel_launch(void* const* d_in, const int* in_sizes, int n_in,
                              void* d_out, int out_size, void* d_ws, size_t ws_size,
                              hipStream_t stream) {
    const float* z = (const float*)d_in[0];
    const float* e = (const float*)d_in[1];
    float* out = (float*)d_out;
    char* ws = (char*)d_ws;

    if (ws_size >= (size_t)WS_NEED) {
        _Float16* zf = (_Float16*)(ws + WS_ZF);
        _Float16* ef = (_Float16*)(ws + WS_EF);
        unsigned long long* wmin = (unsigned long long*)(ws + WS_WMIN);
        float* z2 = (float*)(ws + WS_Z2);
        float* e2 = (float*)(ws + WS_E2);
        unsigned* amin = (unsigned*)(ws + WS_AMIN);
        double* partials = (double*)(ws + WS_PART);

        k_prep<<<(N_ROWS + K_CODES) / 4, 256, 0, stream>>>(z, e, z2, e2, wmin, partials, amin);
        k_conv<<<768, 256, 0, stream>>>(z, e, zf, ef);
        k_mfma<0><<<dim3(128, 8), 256, 0, stream>>>(zf, ef, z2, e2, z, e, amin, wmin);
        k_mfma<1><<<dim3(128, 64), 256, 0, stream>>>(zf, ef, z2, e2, z, e, amin, wmin);
        k_gather<<<N_ROWS, 64, 0, stream>>>(z, e, wmin, out, partials);
        k_finalize<<<1, 64, 0, stream>>>(partials, out + (size_t)N_ROWS * D_DIM);
    } else {
        unsigned long long* wmin = (unsigned long long*)(ws + FB_WMIN);
        float* z2 = (float*)(ws + FB_Z2);
        float* e2 = (float*)(ws + FB_E2);
        double* partials = (double*)(ws + FB_PART);

        k_prep<<<(N_ROWS + K_CODES) / 4, 256, 0, stream>>>(z, e, z2, e2, wmin, partials, nullptr);
        dim3 grid(N_ROWS / BN, KSPLIT);
        k_argmin_fb<<<grid, 256, 0, stream>>>(z, e, z2, e2, wmin);
        k_gather<<<N_ROWS, 64, 0, stream>>>(z, e, wmin, out, partials);
        k_finalize<<<1, 64, 0, stream>>>(partials, out + (size_t)N_ROWS * D_DIM);
    }
}